// Round 9
// baseline (441.893 us; speedup 1.0000x reference)
//
#include <hip/hip_runtime.h>
#include <hip/hip_cooperative_groups.h>

namespace cg = cooperative_groups;

#define LAG 5
#define HID 256
#define NA 30
#define NE 870
#define TM 195
#define TT 200
#define NB 2
#define EPN 29
#define TB3 65                 // 195/3 time-tiles of 3
#define NROWS (NB * TM * NA)   // 11700 (b,t,n) rows
#define APAD 4
#define KC 32
#define VT2 (NB * NA * TB3)    // 3900 phase-2 tiles
#define UVT 366                // phase-1 u,v tiles (32 rows each)
#define FRT 50                 // phase-1 frag tiles (2x 256-thread units each)
#define VT1 (UVT + FRT)        // 416
#define VT3 366                // phase-3 tiles (32 rows each)
#define W2F_ELEMS (HID * HID)
#define W1F_ELEMS (HID * 288)
#define UVB 1463               // fallback k1 u,v blocks

typedef _Float16 f16;
typedef _Float16 f16x8 __attribute__((ext_vector_type(8)));
typedef float floatx4 __attribute__((ext_vector_type(4)));

// ================================================================ fused cooperative kernel
__global__ __launch_bounds__(512, 4) void nri_fused(
    const float* __restrict__ inputs, const float* __restrict__ mu,
    const float* __restrict__ logvar, const float* __restrict__ eps,
    const float* __restrict__ w_msg1, const float* __restrict__ b_msg1,
    const float* __restrict__ w_msg2, const float* __restrict__ b_msg2,
    const float* __restrict__ w_out1, const float* __restrict__ b_out1,
    const float* __restrict__ w_out2, const float* __restrict__ b_out2,
    const float* __restrict__ w_out3, const float* __restrict__ b_out3,
    float* __restrict__ out,
    f16* __restrict__ u, f16* __restrict__ v, f16* __restrict__ aggw,
    f16* __restrict__ w2frag, f16* __restrict__ w1frag, f16* __restrict__ w2ofrag)
{
    __shared__ __align__(16) char smem[49920];   // phase2: a_lds[96][260] ; phase3: a1[32][292]
    __shared__ float ev_lds[32];
    __shared__ float red[8][16];

    cg::grid_group grid = cg::this_grid();

    const int gsz = gridDim.x;
    const int bid = blockIdx.x;
    const int tid = threadIdx.x;
    const int lane = tid & 63;
    const int q = lane >> 4, m15 = lane & 15;

    // ================= PHASE 1: u,v + weight fragments (grid-stride) =================
    for (int vb = bid; vb < VT1; vb += gsz) {
        if (vb < UVT) {
            const int col = tid & 255, half = tid >> 8;
            float w1c[2 * LAG];
            #pragma unroll
            for (int k = 0; k < 2 * LAG; ++k) w1c[k] = w_msg1[k * HID + col];
            const float bb = b_msg1[col];
            const int rbase = vb * 32 + half * 16;
            #pragma unroll
            for (int i = 0; i < 16; ++i) {
                const int r = rbase + i;
                if (r < NROWS) {
                    const int b = r / (TM * NA), rem = r % (TM * NA);
                    const int t = rem / NA, n = rem % NA;
                    const float* ip = inputs + (b * NA + n) * TT + t;
                    float ua = bb, va = 0.f;
                    #pragma unroll
                    for (int l = 0; l < LAG; ++l) {
                        const float f = ip[l];
                        ua = fmaf(f, w1c[l], ua);
                        va = fmaf(f, w1c[LAG + l], va);
                    }
                    u[(r << 8) + col] = (f16)ua;
                    v[(r << 8) + col] = (f16)va;
                }
            }
        } else {
            // weight fragments: chunk = col/16 ; elem offset = ((chunk*KCHUNKS + kc)*64 + lane)*8
            const int vb256 = (vb - UVT) * 2 + (tid >> 8);   // [0,100)
            const int tid256 = tid & 255;
            if (vb256 < 32) {                                  // W2^T frag (8 k-chunks)
                const int fidx = vb256 * 256 + tid256;
                const int ln = fidx & 63;
                const int kc = (fidx >> 6) & 7;
                const int ntc = fidx >> 9;
                const int colw = ntc * 16 + (ln & 15);
                const int kb = kc * KC + (ln >> 4) * 8;
                f16x8 vv;
                #pragma unroll
                for (int x = 0; x < 8; ++x) vv[x] = (f16)w_msg2[(kb + x) * HID + colw];
                *(f16x8*)&w2frag[fidx * 8] = vv;
            } else if (vb256 < 68) {                           // W_out1' frag (9 k-chunks, K=288)
                const int fidx = (vb256 - 32) * 256 + tid256;  // [0,9216)
                const int ln = fidx & 63;
                const int kc = (fidx >> 6) % 9;
                const int ntc = fidx / 576;
                const int colw = ntc * 16 + (ln & 15);
                const int kb = kc * KC + (ln >> 4) * 8;
                f16x8 vv;
                #pragma unroll
                for (int x = 0; x < 8; ++x) {
                    const int k = kb + x;
                    float val;
                    if (k < 256)      val = w_out1[(5 + k) * HID + colw];
                    else if (k < 261) val = w_out1[(k - 256) * HID + colw];
                    else              val = 0.f;
                    vv[x] = (f16)val;
                }
                *(f16x8*)&w1frag[fidx * 8] = vv;
            } else {                                           // W_out2^T frag (8 k-chunks)
                const int fidx = (vb256 - 68) * 256 + tid256;
                const int ln = fidx & 63;
                const int kc = (fidx >> 6) & 7;
                const int ntc = fidx >> 9;
                const int colw = ntc * 16 + (ln & 15);
                const int kb = kc * KC + (ln >> 4) * 8;
                f16x8 vv;
                #pragma unroll
                for (int x = 0; x < 8; ++x) vv[x] = (f16)w_out2[(kb + x) * HID + colw];
                *(f16x8*)&w2ofrag[fidx * 8] = vv;
            }
        }
    }

    grid.sync();

    // ================= PHASE 2: msg MLP + edge-weighted aggregation (grid-stride) =================
    {
        f16 (*a_lds)[HID + APAD] = (f16 (*)[HID + APAD])smem;   // [96][260]
        const int w = tid >> 6;            // 0..7
        const int wbase = w * 32;
        const f16* bbase = w2frag + (lane << 3);
        const f16x8 z8 = {(f16)0, (f16)0, (f16)0, (f16)0, (f16)0, (f16)0, (f16)0, (f16)0};

        for (int vb = bid; vb < VT2; vb += gsz) {
            const int n = vb % NA;
            const int tb = (vb / NA) % TB3;
            const int b = vb / (NA * TB3);
            const int t0 = tb * 3;

            if (tid < 32) {
                float evv = 0.f;
                if (tid < EPN) {
                    const int e = b * NE + n * EPN + tid;
                    evv = eps[e] * __expf(0.5f * logvar[e]) + mu[e];
                }
                ev_lds[tid] = evv;
            }
            // stage A = relu(u[send]+v[recv]) : 96 rows x 32 chunks
            #pragma unroll
            for (int i = 0; i < 6; ++i) {
                const int task = i * 512 + tid;
                const int row = task >> 5, c = task & 31;
                const int tt = row >> 5, ei = row & 31;
                f16x8 out8;
                if (ei < EPN) {
                    const int t = t0 + tt;
                    const int j = ei + (ei >= n);
                    const f16x8 uu = *(const f16x8*)(u + ((((b * TM + t) * NA + j) << 8) + c * 8));
                    const f16x8 vv = *(const f16x8*)(v + ((((b * TM + t) * NA + n) << 8) + c * 8));
                    out8 = __builtin_elementwise_max(uu + vv, z8);
                } else {
                    out8 = z8;
                }
                *(f16x8*)&a_lds[row][c * 8] = out8;
            }
            f16x8 b0[2], b1[2], b2[2];
            #pragma unroll
            for (int nt = 0; nt < 2; ++nt) {
                b0[nt] = *(const f16x8*)(bbase + (((w * 2 + nt) * 8 + 0) << 9));
                b1[nt] = *(const f16x8*)(bbase + (((w * 2 + nt) * 8 + 1) << 9));
            }
            floatx4 acc[6][2];
            #pragma unroll
            for (int mt = 0; mt < 6; ++mt)
                #pragma unroll
                for (int nt = 0; nt < 2; ++nt)
                    acc[mt][nt] = (floatx4){0.f, 0.f, 0.f, 0.f};

            __syncthreads();

            #pragma unroll
            for (int kc = 0; kc < 8; ++kc) {
                if (kc < 6) {
                    #pragma unroll
                    for (int nt = 0; nt < 2; ++nt)
                        b2[nt] = *(const f16x8*)(bbase + (((w * 2 + nt) * 8 + kc + 2) << 9));
                }
                f16x8 af[6];
                #pragma unroll
                for (int mt = 0; mt < 6; ++mt)
                    af[mt] = *(const f16x8*)&a_lds[mt * 16 + m15][kc * KC + q * 8];
                #pragma unroll
                for (int nt = 0; nt < 2; ++nt)
                    #pragma unroll
                    for (int mt = 0; mt < 6; ++mt)
                        acc[mt][nt] = __builtin_amdgcn_mfma_f32_16x16x32_f16(af[mt], b0[nt], acc[mt][nt], 0, 0, 0);
                #pragma unroll
                for (int nt = 0; nt < 2; ++nt) { b0[nt] = b1[nt]; b1[nt] = b2[nt]; }
            }
            // epilogue
            float b2v[2];
            #pragma unroll
            for (int nt = 0; nt < 2; ++nt) b2v[nt] = b_msg2[wbase + nt * 16 + m15];
            #pragma unroll
            for (int tt = 0; tt < 3; ++tt) {
                const int t = t0 + tt;
                #pragma unroll
                for (int nt = 0; nt < 2; ++nt) {
                    float part = 0.f;
                    #pragma unroll
                    for (int ml = 0; ml < 2; ++ml) {
                        const int mt = tt * 2 + ml;
                        #pragma unroll
                        for (int reg = 0; reg < 4; ++reg) {
                            const int ei = (ml * 16 + q * 4 + reg);
                            part += ev_lds[ei] * fmaxf(acc[mt][nt][reg] + b2v[nt], 0.f);
                        }
                    }
                    part += __shfl_xor(part, 16, 64);
                    part += __shfl_xor(part, 32, 64);
                    if (q == 0)
                        aggw[((((b * TM + t) * NA + n) << 8) + wbase + nt * 16 + m15)] = (f16)part;
                }
            }
            __syncthreads();
        }
    }

    grid.sync();

    // ================= PHASE 3: out MLP 288->256->256->1, 32 rows/tile (grid-stride) =================
    {
        f16 (*a1)[288 + APAD] = (f16 (*)[288 + APAD])smem;   // [32][292]
        const int tid256 = tid & 255, half = tid >> 8;
        const int wh = (tid256 >> 6);        // wave within half, 0..3
        const int gw = tid >> 6;             // global wave, 0..7
        const int wbase = wh * 64;
        const f16* b1base = w1frag + (lane << 3);
        const f16* b2base = w2ofrag + (lane << 3);

        for (int vb = bid; vb < VT3; vb += gsz) {
            const int R0 = vb * 32 + half * 16;

            // stage A1 = [agg(256) | feat(5) | 0...]
            #pragma unroll
            for (int i = 0; i < 2; ++i) {
                const int task = i * 256 + tid256;
                const int row = task >> 5, c = task & 31;
                const int R = R0 + row;
                f16x8 val;
                if (R < NROWS) {
                    val = *(const f16x8*)&aggw[(R << 8) + c * 8];
                } else {
                    for (int x = 0; x < 8; ++x) val[x] = (f16)0.f;
                }
                *(f16x8*)&a1[half * 16 + row][c * 8] = val;
            }
            if (tid256 < 16) {
                const int R = R0 + tid256;
                const int lrow = half * 16 + tid256;
                if (R < NROWS) {
                    const int b = R / (TM * NA), rem = R % (TM * NA);
                    const int t = rem / NA, n = rem % NA;
                    const float* ip = inputs + (b * NA + n) * TT + t;
                    #pragma unroll
                    for (int l = 0; l < LAG; ++l) a1[lrow][256 + l] = (f16)ip[l];
                    #pragma unroll
                    for (int k = 261; k < 288; ++k) a1[lrow][k] = (f16)0.f;
                } else {
                    for (int k = 256; k < 288; ++k) a1[lrow][k] = (f16)0.f;
                }
            }

            floatx4 acc[4];
            #pragma unroll
            for (int nt = 0; nt < 4; ++nt) acc[nt] = (floatx4){0.f, 0.f, 0.f, 0.f};

            // GEMM1: K=288 (9 chunks)
            f16x8 bcur[4], bnxt[4];
            #pragma unroll
            for (int nt = 0; nt < 4; ++nt)
                bcur[nt] = *(const f16x8*)(b1base + (((wh * 4 + nt) * 9 + 0) << 9));

            __syncthreads();   // A1 staged

            #pragma unroll
            for (int kc = 0; kc < 9; ++kc) {
                if (kc < 8) {
                    #pragma unroll
                    for (int nt = 0; nt < 4; ++nt)
                        bnxt[nt] = *(const f16x8*)(b1base + (((wh * 4 + nt) * 9 + kc + 1) << 9));
                }
                const f16x8 af = *(const f16x8*)&a1[half * 16 + m15][kc * KC + q * 8];
                #pragma unroll
                for (int nt = 0; nt < 4; ++nt)
                    acc[nt] = __builtin_amdgcn_mfma_f32_16x16x32_f16(af, bcur[nt], acc[nt], 0, 0, 0);
                #pragma unroll
                for (int nt = 0; nt < 4; ++nt) bcur[nt] = bnxt[nt];
            }
            __syncthreads();   // GEMM1 reads of a1 done

            // epilogue1: relu(+b_out1) -> a1
            {
                float b1v[4];
                #pragma unroll
                for (int nt = 0; nt < 4; ++nt) b1v[nt] = b_out1[wbase + nt * 16 + m15];
                #pragma unroll
                for (int nt = 0; nt < 4; ++nt)
                    #pragma unroll
                    for (int reg = 0; reg < 4; ++reg)
                        a1[half * 16 + q * 4 + reg][wbase + nt * 16 + m15] =
                            (f16)fmaxf(acc[nt][reg] + b1v[nt], 0.f);
            }
            #pragma unroll
            for (int nt = 0; nt < 4; ++nt) acc[nt] = (floatx4){0.f, 0.f, 0.f, 0.f};

            // GEMM2: K=256 (8 chunks)
            #pragma unroll
            for (int nt = 0; nt < 4; ++nt)
                bcur[nt] = *(const f16x8*)(b2base + (((wh * 4 + nt) * 8 + 0) << 9));

            __syncthreads();   // epilogue1 writes visible

            #pragma unroll
            for (int kc = 0; kc < 8; ++kc) {
                if (kc < 7) {
                    #pragma unroll
                    for (int nt = 0; nt < 4; ++nt)
                        bnxt[nt] = *(const f16x8*)(b2base + (((wh * 4 + nt) * 8 + kc + 1) << 9));
                }
                const f16x8 af = *(const f16x8*)&a1[half * 16 + m15][kc * KC + q * 8];
                #pragma unroll
                for (int nt = 0; nt < 4; ++nt)
                    acc[nt] = __builtin_amdgcn_mfma_f32_16x16x32_f16(af, bcur[nt], acc[nt], 0, 0, 0);
                #pragma unroll
                for (int nt = 0; nt < 4; ++nt) bcur[nt] = bnxt[nt];
            }

            // epilogue2: relu(+b_out2), dot w_out3, reduce 256 cols
            {
                float b2v[4], w3v[4];
                #pragma unroll
                for (int nt = 0; nt < 4; ++nt) {
                    const int col = wbase + nt * 16 + m15;
                    b2v[nt] = b_out2[col];
                    w3v[nt] = w_out3[col];
                }
                #pragma unroll
                for (int reg = 0; reg < 4; ++reg) {
                    float p = 0.f;
                    #pragma unroll
                    for (int nt = 0; nt < 4; ++nt)
                        p += fmaxf(acc[nt][reg] + b2v[nt], 0.f) * w3v[nt];
                    p += __shfl_xor(p, 1, 64);
                    p += __shfl_xor(p, 2, 64);
                    p += __shfl_xor(p, 4, 64);
                    p += __shfl_xor(p, 8, 64);
                    if (m15 == 0) red[gw][q * 4 + reg] = p;
                }
            }
            __syncthreads();
            if (tid < 32) {
                const int h = tid >> 4, r = tid & 15;
                const int R = vb * 32 + h * 16 + r;
                if (R < NROWS) {
                    const float val = red[h * 4 + 0][r] + red[h * 4 + 1][r] +
                                      red[h * 4 + 2][r] + red[h * 4 + 3][r] + b_out3[0];
                    const int b = R / (TM * NA), rem = R % (TM * NA);
                    const int t = rem / NA, n = rem % NA;
                    out[(b * NA + n) * TM + t] = val;
                }
            }
            __syncthreads();   // red reads done before next tile overwrites
        }
    }
}

// ================================================================ fallback: round-7 three-kernel path
__global__ __launch_bounds__(256) void k1_prep(
    const float* __restrict__ inputs, const float* __restrict__ w_msg1,
    const float* __restrict__ b_msg1, const float* __restrict__ w_msg2,
    const float* __restrict__ w_out1, const float* __restrict__ w_out2,
    f16* __restrict__ u, f16* __restrict__ v, f16* __restrict__ w2frag,
    f16* __restrict__ w1frag, f16* __restrict__ w2ofrag)
{
    const int bid = blockIdx.x, tid = threadIdx.x;
    if (bid < UVB) {
        __shared__ float feats8[8][LAG];
        const int r0 = bid * 8;
        if (tid < 8 * LAG) {
            const int i = tid / LAG, l = tid % LAG;
            const int r = r0 + i;
            float fv = 0.f;
            if (r < NROWS) {
                const int b = r / (TM * NA), rem = r % (TM * NA);
                const int t = rem / NA, n = rem % NA;
                fv = inputs[(b * NA + n) * TT + t + l];
            }
            feats8[i][l] = fv;
        }
        float w1c[2 * LAG];
        #pragma unroll
        for (int k = 0; k < 2 * LAG; ++k) w1c[k] = w_msg1[k * HID + tid];
        const float bb = b_msg1[tid];
        __syncthreads();
        #pragma unroll
        for (int i = 0; i < 8; ++i) {
            const int r = r0 + i;
            if (r < NROWS) {
                float ua = bb, va = 0.f;
                #pragma unroll
                for (int l = 0; l < LAG; ++l) {
                    ua = fmaf(feats8[i][l], w1c[l], ua);
                    va = fmaf(feats8[i][l], w1c[LAG + l], va);
                }
                u[(r << 8) + tid] = (f16)ua;
                v[(r << 8) + tid] = (f16)va;
            }
        }
    } else if (bid < UVB + 32) {
        const int fidx = (bid - UVB) * 256 + tid;
        const int ln = fidx & 63;
        const int kc = (fidx >> 6) & 7;
        const int ntc = fidx >> 9;
        const int col = ntc * 16 + (ln & 15);
        const int kb = kc * KC + (ln >> 4) * 8;
        f16x8 vv;
        #pragma unroll
        for (int x = 0; x < 8; ++x) vv[x] = (f16)w_msg2[(kb + x) * HID + col];
        *(f16x8*)&w2frag[fidx * 8] = vv;
    } else if (bid < UVB + 32 + 36) {
        const int fidx = (bid - (UVB + 32)) * 256 + tid;
        const int ln = fidx & 63;
        const int kc = (fidx >> 6) % 9;
        const int ntc = fidx / 576;
        const int col = ntc * 16 + (ln & 15);
        const int kb = kc * KC + (ln >> 4) * 8;
        f16x8 vv;
        #pragma unroll
        for (int x = 0; x < 8; ++x) {
            const int k = kb + x;
            float val;
            if (k < 256)      val = w_out1[(5 + k) * HID + col];
            else if (k < 261) val = w_out1[(k - 256) * HID + col];
            else              val = 0.f;
            vv[x] = (f16)val;
        }
        *(f16x8*)&w1frag[fidx * 8] = vv;
    } else {
        const int fidx = (bid - (UVB + 32 + 36)) * 256 + tid;
        const int ln = fidx & 63;
        const int kc = (fidx >> 6) & 7;
        const int ntc = fidx >> 9;
        const int col = ntc * 16 + (ln & 15);
        const int kb = kc * KC + (ln >> 4) * 8;
        f16x8 vv;
        #pragma unroll
        for (int x = 0; x < 8; ++x) vv[x] = (f16)w_out2[(kb + x) * HID + col];
        *(f16x8*)&w2ofrag[fidx * 8] = vv;
    }
}

__global__ __launch_bounds__(512, 4) void k2_msg(
    const f16* __restrict__ u, const f16* __restrict__ v,
    const f16* __restrict__ w2frag,
    const float* __restrict__ mu, const float* __restrict__ logvar,
    const float* __restrict__ eps, const float* __restrict__ b_msg2,
    f16* __restrict__ agg)
{
    __shared__ f16 a_lds[96][HID + APAD];
    __shared__ float ev_lds[32];

    const int bid = blockIdx.x;
    const int n  = bid % NA;
    const int tb = (bid / NA) % TB3;
    const int b  = bid / (NA * TB3);
    const int t0 = tb * 3;
    const int tid = threadIdx.x;
    const int lane = tid & 63, w = tid >> 6;
    const int q = lane >> 4, m15 = lane & 15;
    const int wbase = w * 32;

    if (tid < 32) {
        float evv = 0.f;
        if (tid < EPN) {
            const int e = b * NE + n * EPN + tid;
            evv = eps[e] * __expf(0.5f * logvar[e]) + mu[e];
        }
        ev_lds[tid] = evv;
    }

    const f16x8 z8 = {(f16)0, (f16)0, (f16)0, (f16)0, (f16)0, (f16)0, (f16)0, (f16)0};

    #pragma unroll
    for (int i = 0; i < 6; ++i) {
        const int task = i * 512 + tid;
        const int row = task >> 5, c = task & 31;
        const int tt = row >> 5, ei = row & 31;
        f16x8 out8;
        if (ei < EPN) {
            const int t = t0 + tt;
            const int j = ei + (ei >= n);
            const f16x8 uu = *(const f16x8*)(u + ((((b * TM + t) * NA + j) << 8) + c * 8));
            const f16x8 vv = *(const f16x8*)(v + ((((b * TM + t) * NA + n) << 8) + c * 8));
            out8 = __builtin_elementwise_max(uu + vv, z8);
        } else {
            out8 = z8;
        }
        *(f16x8*)&a_lds[row][c * 8] = out8;
    }

    const f16* bbase = w2frag + (lane << 3);
    f16x8 b0[2], b1[2], b2[2];
    #pragma unroll
    for (int nt = 0; nt < 2; ++nt) {
        b0[nt] = *(const f16x8*)(bbase + (((w * 2 + nt) * 8 + 0) << 9));
        b1[nt] = *(const f16x8*)(bbase + (((w * 2 + nt) * 8 + 1) << 9));
    }

    floatx4 acc[6][2];
    #pragma unroll
    for (int mt = 0; mt < 6; ++mt)
        #pragma unroll
        for (int nt = 0; nt < 2; ++nt)
            acc[mt][nt] = (floatx4){0.f, 0.f, 0.f, 0.f};

    __syncthreads();

    #pragma unroll
    for (int kc = 0; kc < 8; ++kc) {
        if (kc < 6) {
            #pragma unroll
            for (int nt = 0; nt < 2; ++nt)
                b2[nt] = *(const f16x8*)(bbase + (((w * 2 + nt) * 8 + kc + 2) << 9));
        }
        f16x8 af[6];
        #pragma unroll
        for (int mt = 0; mt < 6; ++mt)
            af[mt] = *(const f16x8*)&a_lds[mt * 16 + m15][kc * KC + q * 8];
        #pragma unroll
        for (int nt = 0; nt < 2; ++nt)
            #pragma unroll
            for (int mt = 0; mt < 6; ++mt)
                acc[mt][nt] = __builtin_amdgcn_mfma_f32_16x16x32_f16(af[mt], b0[nt], acc[mt][nt], 0, 0, 0);
        #pragma unroll
        for (int nt = 0; nt < 2; ++nt) { b0[nt] = b1[nt]; b1[nt] = b2[nt]; }
    }

    float b2v[2];
    #pragma unroll
    for (int nt = 0; nt < 2; ++nt) b2v[nt] = b_msg2[wbase + nt * 16 + m15];

    #pragma unroll
    for (int tt = 0; tt < 3; ++tt) {
        const int t = t0 + tt;
        #pragma unroll
        for (int nt = 0; nt < 2; ++nt) {
            float part = 0.f;
            #pragma unroll
            for (int ml = 0; ml < 2; ++ml) {
                const int mt = tt * 2 + ml;
                #pragma unroll
                for (int reg = 0; reg < 4; ++reg) {
                    const int ei = (ml * 16 + q * 4 + reg);
                    part += ev_lds[ei] * fmaxf(acc[mt][nt][reg] + b2v[nt], 0.f);
                }
            }
            part += __shfl_xor(part, 16, 64);
            part += __shfl_xor(part, 32, 64);
            if (q == 0)
                agg[((((b * TM + t) * NA + n) << 8) + wbase + nt * 16 + m15)] = (f16)part;
        }
    }
}

__global__ __launch_bounds__(256) void k3_out(
    const f16* __restrict__ agg, const float* __restrict__ inputs,
    const f16* __restrict__ w1frag, const f16* __restrict__ w2ofrag,
    const float* __restrict__ b_out1, const float* __restrict__ b_out2,
    const float* __restrict__ w_out3, const float* __restrict__ b_out3,
    float* __restrict__ out)
{
    __shared__ f16 a1[16][288 + APAD];
    __shared__ float red[4][16];

    const int R0 = blockIdx.x * 16;
    const int tid = threadIdx.x;
    const int lane = tid & 63, w = tid >> 6;
    const int q = lane >> 4, m15 = lane & 15;
    const int wbase = w * 64;

    #pragma unroll
    for (int i = 0; i < 2; ++i) {
        const int task = i * 256 + tid;
        const int row = task >> 5, c = task & 31;
        const int R = R0 + row;
        f16x8 val;
        if (R < NROWS) {
            val = *(const f16x8*)&agg[(R << 8) + c * 8];
        } else {
            for (int x = 0; x < 8; ++x) val[x] = (f16)0.f;
        }
        *(f16x8*)&a1[row][c * 8] = val;
    }
    if (tid < 16) {
        const int R = R0 + tid;
        if (R < NROWS) {
            const int b = R / (TM * NA), rem = R % (TM * NA);
            const int t = rem / NA, n = rem % NA;
            const float* ip = inputs + (b * NA + n) * TT + t;
            #pragma unroll
            for (int l = 0; l < LAG; ++l) a1[tid][256 + l] = (f16)ip[l];
            #pragma unroll
            for (int k = 261; k < 288; ++k) a1[tid][k] = (f16)0.f;
        } else {
            for (int k = 256; k < 288; ++k) a1[tid][k] = (f16)0.f;
        }
    }

    floatx4 acc[4];
    #pragma unroll
    for (int nt = 0; nt < 4; ++nt) acc[nt] = (floatx4){0.f, 0.f, 0.f, 0.f};

    const f16* b1base = w1frag + (lane << 3);
    f16x8 bcur[4], bnxt[4];
    #pragma unroll
    for (int nt = 0; nt < 4; ++nt)
        bcur[nt] = *(const f16x8*)(b1base + (((w * 4 + nt) * 9 + 0) << 9));

    __syncthreads();

    #pragma unroll
    for (int kc = 0; kc < 9; ++kc) {
        if (kc < 8) {
            #pragma unroll
            for (int nt = 0; nt < 4; ++nt)
                bnxt[nt] = *(const f16x8*)(b1base + (((w * 4 + nt) * 9 + kc + 1) << 9));
        }
        const f16x8 af = *(const f16x8*)&a1[m15][kc * KC + q * 8];
        #pragma unroll
        for (int nt = 0; nt < 4; ++nt)
            acc[nt] = __builtin_amdgcn_mfma_f32_16x16x32_f16(af, bcur[nt], acc[nt], 0, 0, 0);
        #pragma unroll
        for (int nt = 0; nt < 4; ++nt) bcur[nt] = bnxt[nt];
    }
    __syncthreads();

    {
        float b1v[4];
        #pragma unroll
        for (int nt = 0; nt < 4; ++nt) b1v[nt] = b_out1[wbase + nt * 16 + m15];
        #pragma unroll
        for (int nt = 0; nt < 4; ++nt)
            #pragma unroll
            for (int reg = 0; reg < 4; ++reg)
                a1[q * 4 + reg][wbase + nt * 16 + m15] =
                    (f16)fmaxf(acc[nt][reg] + b1v[nt], 0.f);
    }
    #pragma unroll
    for (int nt = 0; nt < 4; ++nt) acc[nt] = (floatx4){0.f, 0.f, 0.f, 0.f};

    const f16* b2base = w2ofrag + (lane << 3);
    #pragma unroll
    for (int nt = 0; nt < 4; ++nt)
        bcur[nt] = *(const f16x8*)(b2base + (((w * 4 + nt) * 8 + 0) << 9));

    __syncthreads();

    #pragma unroll
    for (int kc = 0; kc < 8; ++kc) {
        if (kc < 7) {
            #pragma unroll
            for (int nt = 0; nt < 4; ++nt)
                bnxt[nt] = *(const f16x8*)(b2base + (((w * 4 + nt) * 8 + kc + 1) << 9));
        }
        const f16x8 af = *(const f16x8*)&a1[m15][kc * KC + q * 8];
        #pragma unroll
        for (int nt = 0; nt < 4; ++nt)
            acc[nt] = __builtin_amdgcn_mfma_f32_16x16x32_f16(af, bcur[nt], acc[nt], 0, 0, 0);
        #pragma unroll
        for (int nt = 0; nt < 4; ++nt) bcur[nt] = bnxt[nt];
    }

    {
        float b2v[4], w3v[4];
        #pragma unroll
        for (int nt = 0; nt < 4; ++nt) {
            const int col = wbase + nt * 16 + m15;
            b2v[nt] = b_out2[col];
            w3v[nt] = w_out3[col];
        }
        #pragma unroll
        for (int reg = 0; reg < 4; ++reg) {
            float p = 0.f;
            #pragma unroll
            for (int nt = 0; nt < 4; ++nt)
                p += fmaxf(acc[nt][reg] + b2v[nt], 0.f) * w3v[nt];
            p += __shfl_xor(p, 1, 64);
            p += __shfl_xor(p, 2, 64);
            p += __shfl_xor(p, 4, 64);
            p += __shfl_xor(p, 8, 64);
            if (m15 == 0) red[w][q * 4 + reg] = p;
        }
    }
    __syncthreads();
    if (tid < 16) {
        const int R = R0 + tid;
        if (R < NROWS) {
            const float val = red[0][tid] + red[1][tid] + red[2][tid] + red[3][tid] + b_out3[0];
            const int b = R / (TM * NA), rem = R % (TM * NA);
            const int t = rem / NA, n = rem % NA;
            out[(b * NA + n) * TM + t] = val;
        }
    }
}

// ----------------------------------------------------------------
extern "C" void kernel_launch(void* const* d_in, const int* in_sizes, int n_in,
                              void* d_out, int out_size, void* d_ws, size_t ws_size,
                              hipStream_t stream) {
    const float* inputs  = (const float*)d_in[0];
    const float* mu      = (const float*)d_in[1];
    const float* logvar  = (const float*)d_in[2];
    const float* eps     = (const float*)d_in[3];
    const float* w_msg1  = (const float*)d_in[6];
    const float* b_msg1  = (const float*)d_in[7];
    const float* w_msg2  = (const float*)d_in[8];
    const float* b_msg2  = (const float*)d_in[9];
    const float* w_out1  = (const float*)d_in[10];
    const float* b_out1  = (const float*)d_in[11];
    const float* w_out2  = (const float*)d_in[12];
    const float* b_out2  = (const float*)d_in[13];
    const float* w_out3  = (const float*)d_in[14];
    const float* b_out3  = (const float*)d_in[15];
    float* out = (float*)d_out;

    f16* u       = (f16*)d_ws;
    f16* v       = u       + NROWS * HID;
    f16* aggw    = v       + NROWS * HID;
    f16* w2frag  = aggw    + NROWS * HID;
    f16* w1frag  = w2frag  + W2F_ELEMS;
    f16* w2ofrag = w1frag  + W1F_ELEMS;

    // size cooperative grid from the runtime's own occupancy model (host-only, deterministic)
    int maxActive = 0, numCU = 256;
    hipError_t qerr = hipOccupancyMaxActiveBlocksPerMultiprocessor(
        &maxActive, (const void*)nri_fused, 512, 0);
    hipDeviceGetAttribute(&numCU, hipDeviceAttributeMultiprocessorCount, 0);

    hipError_t lerr = hipErrorUnknown;
    if (qerr == hipSuccess && maxActive >= 1) {
        int gridn = maxActive * numCU;
        if (gridn > 512) gridn = 512;
        void* args[] = {
            (void*)&inputs, (void*)&mu, (void*)&logvar, (void*)&eps,
            (void*)&w_msg1, (void*)&b_msg1, (void*)&w_msg2, (void*)&b_msg2,
            (void*)&w_out1, (void*)&b_out1, (void*)&w_out2, (void*)&b_out2,
            (void*)&w_out3, (void*)&b_out3, (void*)&out,
            (void*)&u, (void*)&v, (void*)&aggw,
            (void*)&w2frag, (void*)&w1frag, (void*)&w2ofrag
        };
        lerr = hipLaunchCooperativeKernel((const void*)nri_fused, dim3(gridn), dim3(512),
                                          args, 0, stream);
    }
    if (lerr != hipSuccess) {
        // fallback: proven round-7 three-kernel path
        hipLaunchKernelGGL(k1_prep, dim3(UVB + 32 + 36 + 32), dim3(256), 0, stream,
                           inputs, w_msg1, b_msg1, w_msg2, w_out1, w_out2,
                           u, v, w2frag, w1frag, w2ofrag);
        hipLaunchKernelGGL(k2_msg, dim3(NB * NA * TB3), dim3(512), 0, stream,
                           u, v, w2frag, mu, logvar, eps, b_msg2, aggw);
        hipLaunchKernelGGL(k3_out, dim3((NROWS + 15) / 16), dim3(256), 0, stream,
                           aggw, inputs, w1frag, w2ofrag, b_out1, b_out2, w_out3, b_out3, out);
    }
}

// Round 10
// 349.741 us; speedup vs baseline: 1.2635x; 1.2635x over previous
//
#include <hip/hip_runtime.h>

#define LAG 5
#define HID 256
#define NA 30
#define NE 870
#define TM 195
#define TT 200
#define NB 2
#define EPN 29
#define TB3 65                 // 195/3 time-tiles of 3
#define NROWS (NB * TM * NA)   // 11700
#define APAD 4
#define KC 32
#define UVB 1463               // k1 u,v blocks (8 rows each)
#define W2F_ELEMS (HID * HID)
#define W1F_ELEMS (HID * 288)
#define A1S 292                // a1 row stride (288 + 4 pad)

typedef _Float16 f16;
typedef _Float16 f16x8 __attribute__((ext_vector_type(8)));
typedef float floatx4 __attribute__((ext_vector_type(4)));

// ---------------------------------------------------------------- K1: prep (u,v + frag-order weights)
// Fragment order: chunk = col/16 ; elem offset = ((chunk*KCHUNKS + kc)*64 + lane)*8.
__global__ __launch_bounds__(256) void k1_prep(
    const float* __restrict__ inputs, const float* __restrict__ w_msg1,
    const float* __restrict__ b_msg1, const float* __restrict__ w_msg2,
    const float* __restrict__ w_out1, const float* __restrict__ w_out2,
    f16* __restrict__ u, f16* __restrict__ v, f16* __restrict__ w2frag,
    f16* __restrict__ w1frag, f16* __restrict__ w2ofrag)
{
    const int bid = blockIdx.x, tid = threadIdx.x;
    if (bid < UVB) {
        __shared__ float feats8[8][LAG];
        const int r0 = bid * 8;
        if (tid < 8 * LAG) {
            const int i = tid / LAG, l = tid % LAG;
            const int r = r0 + i;
            float fv = 0.f;
            if (r < NROWS) {
                const int b = r / (TM * NA), rem = r % (TM * NA);
                const int t = rem / NA, n = rem % NA;
                fv = inputs[(b * NA + n) * TT + t + l];
            }
            feats8[i][l] = fv;
        }
        float w1c[2 * LAG];
        #pragma unroll
        for (int k = 0; k < 2 * LAG; ++k) w1c[k] = w_msg1[k * HID + tid];
        const float bb = b_msg1[tid];
        __syncthreads();
        #pragma unroll
        for (int i = 0; i < 8; ++i) {
            const int r = r0 + i;
            if (r < NROWS) {
                float ua = bb, va = 0.f;
                #pragma unroll
                for (int l = 0; l < LAG; ++l) {
                    ua = fmaf(feats8[i][l], w1c[l], ua);
                    va = fmaf(feats8[i][l], w1c[LAG + l], va);
                }
                u[(r << 8) + tid] = (f16)ua;
                v[(r << 8) + tid] = (f16)va;
            }
        }
    } else if (bid < UVB + 32) {                      // W2^T frag (8 k-chunks)
        const int fidx = (bid - UVB) * 256 + tid;
        const int ln = fidx & 63;
        const int kc = (fidx >> 6) & 7;
        const int ntc = fidx >> 9;
        const int col = ntc * 16 + (ln & 15);
        const int kb = kc * KC + (ln >> 4) * 8;
        f16x8 vv;
        #pragma unroll
        for (int x = 0; x < 8; ++x) vv[x] = (f16)w_msg2[(kb + x) * HID + col];
        *(f16x8*)&w2frag[fidx * 8] = vv;
    } else if (bid < UVB + 32 + 36) {                 // W_out1' frag (9 k-chunks, K=288)
        const int fidx = (bid - (UVB + 32)) * 256 + tid;
        const int ln = fidx & 63;
        const int kc = (fidx >> 6) % 9;
        const int ntc = fidx / 576;
        const int col = ntc * 16 + (ln & 15);
        const int kb = kc * KC + (ln >> 4) * 8;
        f16x8 vv;
        #pragma unroll
        for (int x = 0; x < 8; ++x) {
            const int k = kb + x;
            float val;
            if (k < 256)      val = w_out1[(5 + k) * HID + col];
            else if (k < 261) val = w_out1[(k - 256) * HID + col];
            else              val = 0.f;
            vv[x] = (f16)val;
        }
        *(f16x8*)&w1frag[fidx * 8] = vv;
    } else {                                          // W_out2^T frag (8 k-chunks)
        const int fidx = (bid - (UVB + 32 + 36)) * 256 + tid;
        const int ln = fidx & 63;
        const int kc = (fidx >> 6) & 7;
        const int ntc = fidx >> 9;
        const int col = ntc * 16 + (ln & 15);
        const int kb = kc * KC + (ln >> 4) * 8;
        f16x8 vv;
        #pragma unroll
        for (int x = 0; x < 8; ++x) vv[x] = (f16)w_out2[(kb + x) * HID + col];
        *(f16x8*)&w2ofrag[fidx * 8] = vv;
    }
}

// ---------------------------------------------------------------- K2X: msg MLP + aggregation + out MLP
// 512 threads / 8 waves; block per (b, n, t-tile of 3). Block-local barriers only.
__global__ __launch_bounds__(512, 4) void k2x(
    const f16* __restrict__ u, const f16* __restrict__ v,
    const f16* __restrict__ w2frag, const f16* __restrict__ w1frag,
    const f16* __restrict__ w2ofrag,
    const float* __restrict__ mu, const float* __restrict__ logvar,
    const float* __restrict__ eps, const float* __restrict__ b_msg2,
    const float* __restrict__ inputs,
    const float* __restrict__ b_out1, const float* __restrict__ b_out2,
    const float* __restrict__ w_out3, const float* __restrict__ b_out3,
    float* __restrict__ out)
{
    __shared__ __align__(16) char smem[96 * (HID + APAD) * 2];   // 49920 B
    __shared__ float ev_lds[32];
    __shared__ float red[8][4];

    f16 (*a_lds)[HID + APAD] = (f16 (*)[HID + APAD])smem;   // phase-2 A [96][260]
    f16 (*a1)[A1S] = (f16 (*)[A1S])smem;                    // out-MLP A [16][292] (aliases)

    const int bid = blockIdx.x;
    const int n  = bid % NA;
    const int tb = (bid / NA) % TB3;
    const int b  = bid / (NA * TB3);
    const int t0 = tb * 3;
    const int tid = threadIdx.x;
    const int lane = tid & 63, w = tid >> 6;   // w in [0,8)
    const int q = lane >> 4, m15 = lane & 15;
    const int wbase = w * 32;                  // 32-col slice per wave

    if (tid < 32) {
        float evv = 0.f;
        if (tid < EPN) {
            const int e = b * NE + n * EPN + tid;
            evv = eps[e] * __expf(0.5f * logvar[e]) + mu[e];
        }
        ev_lds[tid] = evv;
    }

    const f16x8 z8 = {(f16)0, (f16)0, (f16)0, (f16)0, (f16)0, (f16)0, (f16)0, (f16)0};

    // ---- stage A = relu(u[send]+v[recv]) : 96 rows x 32 chunks ----
    #pragma unroll
    for (int i = 0; i < 6; ++i) {
        const int task = i * 512 + tid;
        const int row = task >> 5, c = task & 31;
        const int tt = row >> 5, ei = row & 31;
        f16x8 out8;
        if (ei < EPN) {
            const int t = t0 + tt;
            const int j = ei + (ei >= n);
            const f16x8 uu = *(const f16x8*)(u + ((((b * TM + t) * NA + j) << 8) + c * 8));
            const f16x8 vv = *(const f16x8*)(v + ((((b * TM + t) * NA + n) << 8) + c * 8));
            out8 = __builtin_elementwise_max(uu + vv, z8);
        } else {
            out8 = z8;
        }
        *(f16x8*)&a_lds[row][c * 8] = out8;
    }

    // ---- phase-2 GEMM: B frag-order (chunk = col/16 = w*2+nt), prefetch depth 2 ----
    const f16* bbase = w2frag + (lane << 3);
    f16x8 b0[2], b1[2], b2[2];
    #pragma unroll
    for (int nt = 0; nt < 2; ++nt) {
        b0[nt] = *(const f16x8*)(bbase + (((w * 2 + nt) * 8 + 0) << 9));
        b1[nt] = *(const f16x8*)(bbase + (((w * 2 + nt) * 8 + 1) << 9));
    }
    floatx4 acc[6][2];
    #pragma unroll
    for (int mt = 0; mt < 6; ++mt)
        #pragma unroll
        for (int nt = 0; nt < 2; ++nt)
            acc[mt][nt] = (floatx4){0.f, 0.f, 0.f, 0.f};

    __syncthreads();   // A staged

    #pragma unroll
    for (int kc = 0; kc < 8; ++kc) {
        if (kc < 6) {
            #pragma unroll
            for (int nt = 0; nt < 2; ++nt)
                b2[nt] = *(const f16x8*)(bbase + (((w * 2 + nt) * 8 + kc + 2) << 9));
        }
        f16x8 af[6];
        #pragma unroll
        for (int mt = 0; mt < 6; ++mt)
            af[mt] = *(const f16x8*)&a_lds[mt * 16 + m15][kc * KC + q * 8];
        #pragma unroll
        for (int nt = 0; nt < 2; ++nt)
            #pragma unroll
            for (int mt = 0; mt < 6; ++mt)
                acc[mt][nt] = __builtin_amdgcn_mfma_f32_16x16x32_f16(af[mt], b0[nt], acc[mt][nt], 0, 0, 0);
        #pragma unroll
        for (int nt = 0; nt < 2; ++nt) { b0[nt] = b1[nt]; b1[nt] = b2[nt]; }
    }

    // ---- agg epilogue (registers only): part[tt][nt] = sum_ei ev*relu(msg) ----
    float b2v[2];
    #pragma unroll
    for (int nt = 0; nt < 2; ++nt) b2v[nt] = b_msg2[wbase + nt * 16 + m15];
    float aggp[3][2];
    #pragma unroll
    for (int tt = 0; tt < 3; ++tt) {
        #pragma unroll
        for (int nt = 0; nt < 2; ++nt) {
            float part = 0.f;
            #pragma unroll
            for (int ml = 0; ml < 2; ++ml) {
                const int mt = tt * 2 + ml;
                #pragma unroll
                for (int reg = 0; reg < 4; ++reg) {
                    const int ei = (ml * 16 + q * 4 + reg);
                    part += ev_lds[ei] * fmaxf(acc[mt][nt][reg] + b2v[nt], 0.f);
                }
            }
            part += __shfl_xor(part, 16, 64);
            part += __shfl_xor(part, 32, 64);
            aggp[tt][nt] = part;
        }
    }

    __syncthreads();   // all K-loop LDS reads done before aliasing a_lds as a1

    // ---- build out-MLP input a1[0..2] = [agg(256) | feat(5) | pad] (rows 3..15 junk, unused outputs) ----
    if (q == 0) {
        #pragma unroll
        for (int tt = 0; tt < 3; ++tt)
            #pragma unroll
            for (int nt = 0; nt < 2; ++nt)
                a1[tt][wbase + nt * 16 + m15] = (f16)aggp[tt][nt];
    }
    if (tid < 3) {
        const float* ip = inputs + (b * NA + n) * TT + t0 + tid;
        #pragma unroll
        for (int l = 0; l < LAG; ++l) a1[tid][256 + l] = (f16)ip[l];
        #pragma unroll
        for (int k = 261; k < 288; ++k) a1[tid][k] = (f16)0.f;
    }
    __syncthreads();

    // ---- out GEMM1: K=288 (9 chunks), single 16-row M-tile ----
    floatx4 oacc[2];
    #pragma unroll
    for (int nt = 0; nt < 2; ++nt) oacc[nt] = (floatx4){0.f, 0.f, 0.f, 0.f};
    const f16* b1b = w1frag + (lane << 3);
    f16x8 c0[2], c1[2];
    #pragma unroll
    for (int nt = 0; nt < 2; ++nt)
        c0[nt] = *(const f16x8*)(b1b + (((w * 2 + nt) * 9 + 0) << 9));
    #pragma unroll
    for (int kc = 0; kc < 9; ++kc) {
        if (kc < 8) {
            #pragma unroll
            for (int nt = 0; nt < 2; ++nt)
                c1[nt] = *(const f16x8*)(b1b + (((w * 2 + nt) * 9 + kc + 1) << 9));
        }
        const f16x8 af = *(const f16x8*)&a1[m15][kc * KC + q * 8];
        #pragma unroll
        for (int nt = 0; nt < 2; ++nt)
            oacc[nt] = __builtin_amdgcn_mfma_f32_16x16x32_f16(af, c0[nt], oacc[nt], 0, 0, 0);
        #pragma unroll
        for (int nt = 0; nt < 2; ++nt) c0[nt] = c1[nt];
    }
    __syncthreads();   // GEMM1 reads of a1 done

    // ---- epilogue1: out1 = relu(oacc + b_out1) -> a1 rows 0..15 ----
    {
        float b1v[2];
        #pragma unroll
        for (int nt = 0; nt < 2; ++nt) b1v[nt] = b_out1[wbase + nt * 16 + m15];
        #pragma unroll
        for (int nt = 0; nt < 2; ++nt)
            #pragma unroll
            for (int reg = 0; reg < 4; ++reg)
                a1[q * 4 + reg][wbase + nt * 16 + m15] =
                    (f16)fmaxf(oacc[nt][reg] + b1v[nt], 0.f);
    }
    __syncthreads();

    // ---- out GEMM2: K=256 (8 chunks) ----
    #pragma unroll
    for (int nt = 0; nt < 2; ++nt) oacc[nt] = (floatx4){0.f, 0.f, 0.f, 0.f};
    const f16* b2b = w2ofrag + (lane << 3);
    #pragma unroll
    for (int nt = 0; nt < 2; ++nt)
        c0[nt] = *(const f16x8*)(b2b + (((w * 2 + nt) * 8 + 0) << 9));
    #pragma unroll
    for (int kc = 0; kc < 8; ++kc) {
        if (kc < 7) {
            #pragma unroll
            for (int nt = 0; nt < 2; ++nt)
                c1[nt] = *(const f16x8*)(b2b + (((w * 2 + nt) * 8 + kc + 1) << 9));
        }
        const f16x8 af = *(const f16x8*)&a1[m15][kc * KC + q * 8];
        #pragma unroll
        for (int nt = 0; nt < 2; ++nt)
            oacc[nt] = __builtin_amdgcn_mfma_f32_16x16x32_f16(af, c0[nt], oacc[nt], 0, 0, 0);
        #pragma unroll
        for (int nt = 0; nt < 2; ++nt) c0[nt] = c1[nt];
    }

    // ---- epilogue2: relu(+b_out2) dot w_out3, reduce 32 cols/wave then 8 waves ----
    {
        float b2o[2], w3v[2];
        #pragma unroll
        for (int nt = 0; nt < 2; ++nt) {
            const int col = wbase + nt * 16 + m15;
            b2o[nt] = b_out2[col];
            w3v[nt] = w_out3[col];
        }
        #pragma unroll
        for (int reg = 0; reg < 4; ++reg) {
            float p = 0.f;
            #pragma unroll
            for (int nt = 0; nt < 2; ++nt)
                p += fmaxf(oacc[nt][reg] + b2o[nt], 0.f) * w3v[nt];
            p += __shfl_xor(p, 1, 64);
            p += __shfl_xor(p, 2, 64);
            p += __shfl_xor(p, 4, 64);
            p += __shfl_xor(p, 8, 64);
            if (m15 == 0 && q == 0 && reg < 3) red[w][reg] = p;   // rows 0..2 only
        }
    }
    __syncthreads();
    if (tid < 3) {
        float val = b_out3[0];
        #pragma unroll
        for (int w8 = 0; w8 < 8; ++w8) val += red[w8][tid];
        out[(b * NA + n) * TM + t0 + tid] = val;
    }
}

// ----------------------------------------------------------------
extern "C" void kernel_launch(void* const* d_in, const int* in_sizes, int n_in,
                              void* d_out, int out_size, void* d_ws, size_t ws_size,
                              hipStream_t stream) {
    const float* inputs  = (const float*)d_in[0];
    const float* mu      = (const float*)d_in[1];
    const float* logvar  = (const float*)d_in[2];
    const float* eps     = (const float*)d_in[3];
    const float* w_msg1  = (const float*)d_in[6];
    const float* b_msg1  = (const float*)d_in[7];
    const float* w_msg2  = (const float*)d_in[8];
    const float* b_msg2  = (const float*)d_in[9];
    const float* w_out1  = (const float*)d_in[10];
    const float* b_out1  = (const float*)d_in[11];
    const float* w_out2  = (const float*)d_in[12];
    const float* b_out2  = (const float*)d_in[13];
    const float* w_out3  = (const float*)d_in[14];
    const float* b_out3  = (const float*)d_in[15];
    float* out = (float*)d_out;

    f16* u       = (f16*)d_ws;
    f16* v       = u       + NROWS * HID;
    f16* w2frag  = v       + NROWS * HID;
    f16* w1frag  = w2frag  + W2F_ELEMS;
    f16* w2ofrag = w1frag  + W1F_ELEMS;   // total ~12.4 MB

    hipLaunchKernelGGL(k1_prep, dim3(UVB + 32 + 36 + 32), dim3(256), 0, stream,
                       inputs, w_msg1, b_msg1, w_msg2, w_out1, w_out2,
                       u, v, w2frag, w1frag, w2ofrag);
    hipLaunchKernelGGL(k2x, dim3(NB * NA * TB3), dim3(512), 0, stream,
                       u, v, w2frag, w1frag, w2ofrag,
                       mu, logvar, eps, b_msg2, inputs,
                       b_out1, b_out2, w_out3, b_out3, out);
}

// Round 11
// 273.123 us; speedup vs baseline: 1.6179x; 1.2805x over previous
//
#include <hip/hip_runtime.h>

#define LAG 5
#define HID 256
#define NA 30
#define NE 870
#define TM 195
#define TT 200
#define NB 2
#define EPN 29
#define TB3 65                 // 195/3 time-tiles of 3
#define NROWS (NB * TM * NA)   // 11700
#define APAD 4
#define KC 32
#define W2F_ELEMS (HID * HID)
#define W1F_ELEMS (HID * 288)

typedef _Float16 f16;
typedef _Float16 f16x8 __attribute__((ext_vector_type(8)));
typedef float floatx4 __attribute__((ext_vector_type(4)));

// ---------------------------------------------------------------- K1: weight fragments only (100 blocks)
// Fragment order: chunk = col/16 ; elem offset = ((chunk*KCHUNKS + kc)*64 + lane)*8.
// Lane holds B[col = chunk*16+(lane&15)][k = kc*32+(lane>>4)*8 .. +8].
__global__ __launch_bounds__(256) void k1_frag(
    const float* __restrict__ w_msg2, const float* __restrict__ w_out1,
    const float* __restrict__ w_out2,
    f16* __restrict__ w2frag, f16* __restrict__ w1frag, f16* __restrict__ w2ofrag)
{
    const int bid = blockIdx.x, tid = threadIdx.x;
    if (bid < 32) {                                   // W2^T frag (8 k-chunks)
        const int fidx = bid * 256 + tid;
        const int ln = fidx & 63;
        const int kc = (fidx >> 6) & 7;
        const int ntc = fidx >> 9;
        const int col = ntc * 16 + (ln & 15);
        const int kb = kc * KC + (ln >> 4) * 8;
        f16x8 vv;
        #pragma unroll
        for (int x = 0; x < 8; ++x) vv[x] = (f16)w_msg2[(kb + x) * HID + col];
        *(f16x8*)&w2frag[fidx * 8] = vv;
    } else if (bid < 32 + 36) {                       // W_out1' frag (9 k-chunks, K=288)
        const int fidx = (bid - 32) * 256 + tid;      // [0, 9216)
        const int ln = fidx & 63;
        const int kc = (fidx >> 6) % 9;
        const int ntc = fidx / 576;
        const int col = ntc * 16 + (ln & 15);
        const int kb = kc * KC + (ln >> 4) * 8;
        f16x8 vv;
        #pragma unroll
        for (int x = 0; x < 8; ++x) {
            const int k = kb + x;
            float val;
            if (k < 256)      val = w_out1[(5 + k) * HID + col];   // agg part (rows 5..260)
            else if (k < 261) val = w_out1[(k - 256) * HID + col]; // feat part (rows 0..4)
            else              val = 0.f;                           // K-pad
            vv[x] = (f16)val;
        }
        *(f16x8*)&w1frag[fidx * 8] = vv;
    } else {                                          // W_out2^T frag (8 k-chunks)
        const int fidx = (bid - 68) * 256 + tid;
        const int ln = fidx & 63;
        const int kc = (fidx >> 6) & 7;
        const int ntc = fidx >> 9;
        const int col = ntc * 16 + (ln & 15);
        const int kb = kc * KC + (ln >> 4) * 8;
        f16x8 vv;
        #pragma unroll
        for (int x = 0; x < 8; ++x) vv[x] = (f16)w_out2[(kb + x) * HID + col];
        *(f16x8*)&w2ofrag[fidx * 8] = vv;
    }
}

// ---------------------------------------------------------------- K2: msg MLP + edge-weighted aggregation
// 512 threads / 8 waves; block per (b, n, t-tile of 3). M=96, N=256 (32/wave), K=256.
// u,v computed IN-BLOCK from inputs+w_msg1 (no u/v global roundtrip).
// B from frag-order global (coalesced), prefetch depth 2, block-local barriers only.
__global__ __launch_bounds__(512, 6) void k2_msg(
    const float* __restrict__ inputs, const float* __restrict__ w_msg1,
    const float* __restrict__ b_msg1,
    const f16* __restrict__ w2frag,
    const float* __restrict__ mu, const float* __restrict__ logvar,
    const float* __restrict__ eps, const float* __restrict__ b_msg2,
    f16* __restrict__ agg)
{
    __shared__ f16 a_lds[96][HID + APAD];      // 49,920 B -> 3 blocks/CU
    __shared__ float ev_lds[32];
    __shared__ float feats[NA][8];             // lag window t0..t0+6 (960 B)

    const int bid = blockIdx.x;
    const int n  = bid % NA;
    const int tb = (bid / NA) % TB3;
    const int b  = bid / (NA * TB3);
    const int t0 = tb * 3;
    const int tid = threadIdx.x;
    const int lane = tid & 63, w = tid >> 6;   // w in [0,8)
    const int q = lane >> 4, m15 = lane & 15;
    const int wbase = w * 32;                  // 32-col slice per wave

    // ---- stage feats + edge scalars ----
    if (tid < NA * 7) {
        const int j = tid / 7, i = tid % 7;
        feats[j][i] = inputs[(b * NA + j) * TT + t0 + i];
    }
    if (tid >= 480) {
        const int e8 = tid - 480;
        float evv = 0.f;
        if (e8 < EPN) {
            const int e = b * NE + n * EPN + e8;
            evv = eps[e] * __expf(0.5f * logvar[e]) + mu[e];
        }
        ev_lds[e8] = evv;
    }
    __syncthreads();

    // ---- compute A = relu(u[send]+v[recv]) directly (in-block msg1) ----
    {
        const int col = tid & 255, dup = tid >> 8;
        float w1c[2 * LAG];
        #pragma unroll
        for (int k = 0; k < 2 * LAG; ++k) w1c[k] = w_msg1[k * HID + col];
        const float bm = b_msg1[col];
        float vacc[3];
        #pragma unroll
        for (int tt = 0; tt < 3; ++tt) {
            float va = 0.f;
            #pragma unroll
            for (int l = 0; l < LAG; ++l) va = fmaf(feats[n][tt + l], w1c[LAG + l], va);
            vacc[tt] = va;
        }
        #pragma unroll
        for (int tt = 0; tt < 3; ++tt) {
            #pragma unroll
            for (int e8 = 0; e8 < 16; ++e8) {
                const int ei = dup * 16 + e8;
                f16 val = (f16)0.f;
                if (ei < EPN) {
                    const int j = ei + (ei >= n);
                    float ua = bm;
                    #pragma unroll
                    for (int l = 0; l < LAG; ++l) ua = fmaf(feats[j][tt + l], w1c[l], ua);
                    val = (f16)fmaxf(ua + vacc[tt], 0.f);
                }
                a_lds[tt * 32 + ei][col] = val;
            }
        }
    }

    // ---- B prefetch (frag-order: chunk = col/16 = w*2+nt) ----
    const f16* bbase = w2frag + (lane << 3);
    f16x8 b0[2], b1[2], b2[2];
    #pragma unroll
    for (int nt = 0; nt < 2; ++nt) {
        b0[nt] = *(const f16x8*)(bbase + (((w * 2 + nt) * 8 + 0) << 9));
        b1[nt] = *(const f16x8*)(bbase + (((w * 2 + nt) * 8 + 1) << 9));
    }
    floatx4 acc[6][2];
    #pragma unroll
    for (int mt = 0; mt < 6; ++mt)
        #pragma unroll
        for (int nt = 0; nt < 2; ++nt)
            acc[mt][nt] = (floatx4){0.f, 0.f, 0.f, 0.f};

    __syncthreads();   // A staged

    #pragma unroll
    for (int kc = 0; kc < 8; ++kc) {
        if (kc < 6) {
            #pragma unroll
            for (int nt = 0; nt < 2; ++nt)
                b2[nt] = *(const f16x8*)(bbase + (((w * 2 + nt) * 8 + kc + 2) << 9));
        }
        f16x8 af[6];
        #pragma unroll
        for (int mt = 0; mt < 6; ++mt)
            af[mt] = *(const f16x8*)&a_lds[mt * 16 + m15][kc * KC + q * 8];
        #pragma unroll
        for (int nt = 0; nt < 2; ++nt)
            #pragma unroll
            for (int mt = 0; mt < 6; ++mt)
                acc[mt][nt] = __builtin_amdgcn_mfma_f32_16x16x32_f16(af[mt], b0[nt], acc[mt][nt], 0, 0, 0);
        #pragma unroll
        for (int nt = 0; nt < 2; ++nt) { b0[nt] = b1[nt]; b1[nt] = b2[nt]; }
    }

    // ---- epilogue: msg = relu(acc + b2) * edgeval ; sum edges -> agg[b,t,n,:] ----
    float b2v[2];
    #pragma unroll
    for (int nt = 0; nt < 2; ++nt) b2v[nt] = b_msg2[wbase + nt * 16 + m15];

    #pragma unroll
    for (int tt = 0; tt < 3; ++tt) {
        const int t = t0 + tt;
        #pragma unroll
        for (int nt = 0; nt < 2; ++nt) {
            float part = 0.f;
            #pragma unroll
            for (int ml = 0; ml < 2; ++ml) {
                const int mt = tt * 2 + ml;
                #pragma unroll
                for (int reg = 0; reg < 4; ++reg) {
                    const int ei = (ml * 16 + q * 4 + reg);    // C-layout row = q*4+reg
                    part += ev_lds[ei] * fmaxf(acc[mt][nt][reg] + b2v[nt], 0.f);
                }
            }
            part += __shfl_xor(part, 16, 64);
            part += __shfl_xor(part, 32, 64);
            if (q == 0)
                agg[((((b * TM + t) * NA + n) << 8) + wbase + nt * 16 + m15)] = (f16)part;
        }
    }
}

// ---------------------------------------------------------------- K3: out MLP 288->256->256->1 (r7-proven)
__global__ __launch_bounds__(256) void k3_out(
    const f16* __restrict__ agg, const float* __restrict__ inputs,
    const f16* __restrict__ w1frag, const f16* __restrict__ w2ofrag,
    const float* __restrict__ b_out1, const float* __restrict__ b_out2,
    const float* __restrict__ w_out3, const float* __restrict__ b_out3,
    float* __restrict__ out)
{
    __shared__ f16 a1[16][288 + APAD];
    __shared__ float red[4][16];

    const int R0 = blockIdx.x * 16;
    const int tid = threadIdx.x;
    const int lane = tid & 63, w = tid >> 6;
    const int q = lane >> 4, m15 = lane & 15;
    const int wbase = w * 64;

    #pragma unroll
    for (int i = 0; i < 2; ++i) {
        const int task = i * 256 + tid;
        const int row = task >> 5, c = task & 31;
        const int R = R0 + row;
        f16x8 val;
        if (R < NROWS) {
            val = *(const f16x8*)&agg[(R << 8) + c * 8];
        } else {
            for (int x = 0; x < 8; ++x) val[x] = (f16)0.f;
        }
        *(f16x8*)&a1[row][c * 8] = val;
    }
    if (tid < 16) {
        const int R = R0 + tid;
        if (R < NROWS) {
            const int b = R / (TM * NA), rem = R % (TM * NA);
            const int t = rem / NA, n = rem % NA;
            const float* ip = inputs + (b * NA + n) * TT + t;
            #pragma unroll
            for (int l = 0; l < LAG; ++l) a1[tid][256 + l] = (f16)ip[l];
            #pragma unroll
            for (int k = 261; k < 288; ++k) a1[tid][k] = (f16)0.f;
        } else {
            for (int k = 256; k < 288; ++k) a1[tid][k] = (f16)0.f;
        }
    }

    floatx4 acc[4];
    #pragma unroll
    for (int nt = 0; nt < 4; ++nt) acc[nt] = (floatx4){0.f, 0.f, 0.f, 0.f};

    const f16* b1base = w1frag + (lane << 3);
    f16x8 bcur[4], bnxt[4];
    #pragma unroll
    for (int nt = 0; nt < 4; ++nt)
        bcur[nt] = *(const f16x8*)(b1base + (((w * 4 + nt) * 9 + 0) << 9));

    __syncthreads();

    #pragma unroll
    for (int kc = 0; kc < 9; ++kc) {
        if (kc < 8) {
            #pragma unroll
            for (int nt = 0; nt < 4; ++nt)
                bnxt[nt] = *(const f16x8*)(b1base + (((w * 4 + nt) * 9 + kc + 1) << 9));
        }
        const f16x8 af = *(const f16x8*)&a1[m15][kc * KC + q * 8];
        #pragma unroll
        for (int nt = 0; nt < 4; ++nt)
            acc[nt] = __builtin_amdgcn_mfma_f32_16x16x32_f16(af, bcur[nt], acc[nt], 0, 0, 0);
        #pragma unroll
        for (int nt = 0; nt < 4; ++nt) bcur[nt] = bnxt[nt];
    }
    __syncthreads();

    {
        float b1v[4];
        #pragma unroll
        for (int nt = 0; nt < 4; ++nt) b1v[nt] = b_out1[wbase + nt * 16 + m15];
        #pragma unroll
        for (int nt = 0; nt < 4; ++nt)
            #pragma unroll
            for (int reg = 0; reg < 4; ++reg)
                a1[q * 4 + reg][wbase + nt * 16 + m15] =
                    (f16)fmaxf(acc[nt][reg] + b1v[nt], 0.f);
    }
    #pragma unroll
    for (int nt = 0; nt < 4; ++nt) acc[nt] = (floatx4){0.f, 0.f, 0.f, 0.f};

    const f16* b2base = w2ofrag + (lane << 3);
    #pragma unroll
    for (int nt = 0; nt < 4; ++nt)
        bcur[nt] = *(const f16x8*)(b2base + (((w * 4 + nt) * 8 + 0) << 9));

    __syncthreads();

    #pragma unroll
    for (int kc = 0; kc < 8; ++kc) {
        if (kc < 7) {
            #pragma unroll
            for (int nt = 0; nt < 4; ++nt)
                bnxt[nt] = *(const f16x8*)(b2base + (((w * 4 + nt) * 8 + kc + 1) << 9));
        }
        const f16x8 af = *(const f16x8*)&a1[m15][kc * KC + q * 8];
        #pragma unroll
        for (int nt = 0; nt < 4; ++nt)
            acc[nt] = __builtin_amdgcn_mfma_f32_16x16x32_f16(af, bcur[nt], acc[nt], 0, 0, 0);
        #pragma unroll
        for (int nt = 0; nt < 4; ++nt) bcur[nt] = bnxt[nt];
    }

    {
        float b2v[4], w3v[4];
        #pragma unroll
        for (int nt = 0; nt < 4; ++nt) {
            const int col = wbase + nt * 16 + m15;
            b2v[nt] = b_out2[col];
            w3v[nt] = w_out3[col];
        }
        #pragma unroll
        for (int reg = 0; reg < 4; ++reg) {
            float p = 0.f;
            #pragma unroll
            for (int nt = 0; nt < 4; ++nt)
                p += fmaxf(acc[nt][reg] + b2v[nt], 0.f) * w3v[nt];
            p += __shfl_xor(p, 1, 64);
            p += __shfl_xor(p, 2, 64);
            p += __shfl_xor(p, 4, 64);
            p += __shfl_xor(p, 8, 64);
            if (m15 == 0) red[w][q * 4 + reg] = p;
        }
    }
    __syncthreads();
    if (tid < 16) {
        const int R = R0 + tid;
        if (R < NROWS) {
            const float val = red[0][tid] + red[1][tid] + red[2][tid] + red[3][tid] + b_out3[0];
            const int b = R / (TM * NA), rem = R % (TM * NA);
            const int t = rem / NA, n = rem % NA;
            out[(b * NA + n) * TM + t] = val;
        }
    }
}

// ----------------------------------------------------------------
extern "C" void kernel_launch(void* const* d_in, const int* in_sizes, int n_in,
                              void* d_out, int out_size, void* d_ws, size_t ws_size,
                              hipStream_t stream) {
    const float* inputs  = (const float*)d_in[0];
    const float* mu      = (const float*)d_in[1];
    const float* logvar  = (const float*)d_in[2];
    const float* eps     = (const float*)d_in[3];
    const float* w_msg1  = (const float*)d_in[6];
    const float* b_msg1  = (const float*)d_in[7];
    const float* w_msg2  = (const float*)d_in[8];
    const float* b_msg2  = (const float*)d_in[9];
    const float* w_out1  = (const float*)d_in[10];
    const float* b_out1  = (const float*)d_in[11];
    const float* w_out2  = (const float*)d_in[12];
    const float* b_out2  = (const float*)d_in[13];
    const float* w_out3  = (const float*)d_in[14];
    const float* b_out3  = (const float*)d_in[15];
    float* out = (float*)d_out;

    // workspace (f16): aggw (6 MB) + frag-order W2, Wout1, Wout2 (~0.54 MB)
    f16* aggw    = (f16*)d_ws;
    f16* w2frag  = aggw    + NROWS * HID;
    f16* w1frag  = w2frag  + W2F_ELEMS;
    f16* w2ofrag = w1frag  + W1F_ELEMS;

    hipLaunchKernelGGL(k1_frag, dim3(100), dim3(256), 0, stream,
                       w_msg2, w_out1, w_out2, w2frag, w1frag, w2ofrag);
    hipLaunchKernelGGL(k2_msg, dim3(NB * NA * TB3), dim3(512), 0, stream,
                       inputs, w_msg1, b_msg1, w2frag, mu, logvar, eps, b_msg2, aggw);
    hipLaunchKernelGGL(k3_out, dim3((NROWS + 15) / 16), dim3(256), 0, stream,
                       aggw, inputs, w1frag, w2ofrag, b_out1, b_out2, w_out3, b_out3, out);
}

// Round 12
// 174.405 us; speedup vs baseline: 2.5337x; 1.5660x over previous
//
#include <hip/hip_runtime.h>

#define LAG 5
#define HID 256
#define NA 30
#define NE 870
#define TM 195
#define TT 200
#define NB 2
#define EPN 29
#define TB3 65                 // 195/3 time-tiles of 3
#define NROWS (NB * TM * NA)   // 11700
#define APAD 4
#define KC 32
#define W2F_ELEMS (HID * HID)
#define W1F_ELEMS (HID * 288)

typedef _Float16 f16;
typedef _Float16 f16x8 __attribute__((ext_vector_type(8)));
typedef float floatx4 __attribute__((ext_vector_type(4)));

// ---------------------------------------------------------------- K1: weight fragments only (100 blocks)
// Fragment order: chunk = col/16 ; elem offset = ((chunk*KCHUNKS + kc)*64 + lane)*8.
__global__ __launch_bounds__(256) void k1_frag(
    const float* __restrict__ w_msg2, const float* __restrict__ w_out1,
    const float* __restrict__ w_out2,
    f16* __restrict__ w2frag, f16* __restrict__ w1frag, f16* __restrict__ w2ofrag)
{
    const int bid = blockIdx.x, tid = threadIdx.x;
    if (bid < 32) {                                   // W2^T frag (8 k-chunks)
        const int fidx = bid * 256 + tid;
        const int ln = fidx & 63;
        const int kc = (fidx >> 6) & 7;
        const int ntc = fidx >> 9;
        const int col = ntc * 16 + (ln & 15);
        const int kb = kc * KC + (ln >> 4) * 8;
        f16x8 vv;
        #pragma unroll
        for (int x = 0; x < 8; ++x) vv[x] = (f16)w_msg2[(kb + x) * HID + col];
        *(f16x8*)&w2frag[fidx * 8] = vv;
    } else if (bid < 32 + 36) {                       // W_out1' frag (9 k-chunks, K=288)
        const int fidx = (bid - 32) * 256 + tid;      // [0, 9216)
        const int ln = fidx & 63;
        const int kc = (fidx >> 6) % 9;
        const int ntc = fidx / 576;
        const int col = ntc * 16 + (ln & 15);
        const int kb = kc * KC + (ln >> 4) * 8;
        f16x8 vv;
        #pragma unroll
        for (int x = 0; x < 8; ++x) {
            const int k = kb + x;
            float val;
            if (k < 256)      val = w_out1[(5 + k) * HID + col];   // agg part (rows 5..260)
            else if (k < 261) val = w_out1[(k - 256) * HID + col]; // feat part (rows 0..4)
            else              val = 0.f;                           // K-pad
            vv[x] = (f16)val;
        }
        *(f16x8*)&w1frag[fidx * 8] = vv;
    } else {                                          // W_out2^T frag (8 k-chunks)
        const int fidx = (bid - 68) * 256 + tid;
        const int ln = fidx & 63;
        const int kc = (fidx >> 6) & 7;
        const int ntc = fidx >> 9;
        const int col = ntc * 16 + (ln & 15);
        const int kb = kc * KC + (ln >> 4) * 8;
        f16x8 vv;
        #pragma unroll
        for (int x = 0; x < 8; ++x) vv[x] = (f16)w_out2[(kb + x) * HID + col];
        *(f16x8*)&w2ofrag[fidx * 8] = vv;
    }
}

// ---------------------------------------------------------------- K2: msg MLP + edge-weighted aggregation
// 512 threads / 8 waves; block per (b, n, t-tile of 3). M=96, N=256 (32/wave), K=256.
// u,v computed IN-BLOCK from inputs+w_msg1. launch_bounds (512,4): VGPR cap 128, no spill.
__global__ __launch_bounds__(512, 4) void k2_msg(
    const float* __restrict__ inputs, const float* __restrict__ w_msg1,
    const float* __restrict__ b_msg1,
    const f16* __restrict__ w2frag,
    const float* __restrict__ mu, const float* __restrict__ logvar,
    const float* __restrict__ eps, const float* __restrict__ b_msg2,
    f16* __restrict__ agg)
{
    __shared__ f16 a_lds[96][HID + APAD];      // 49,920 B
    __shared__ float ev_lds[32];
    __shared__ float feats[NA][8];             // lag window t0..t0+6 (960 B)

    const int bid = blockIdx.x;
    const int n  = bid % NA;
    const int tb = (bid / NA) % TB3;
    const int b  = bid / (NA * TB3);
    const int t0 = tb * 3;
    const int tid = threadIdx.x;
    const int lane = tid & 63, w = tid >> 6;   // w in [0,8)
    const int q = lane >> 4, m15 = lane & 15;
    const int wbase = w * 32;                  // 32-col slice per wave

    // ---- stage feats + edge scalars ----
    if (tid < NA * 7) {
        const int j = tid / 7, i = tid % 7;
        feats[j][i] = inputs[(b * NA + j) * TT + t0 + i];
    }
    if (tid >= 480) {
        const int e8 = tid - 480;
        float evv = 0.f;
        if (e8 < EPN) {
            const int e = b * NE + n * EPN + e8;
            evv = eps[e] * __expf(0.5f * logvar[e]) + mu[e];
        }
        ev_lds[e8] = evv;
    }
    __syncthreads();

    // ---- compute A = relu(u[send]+v[recv]) directly (in-block msg1) ----
    {
        const int col = tid & 255, dup = tid >> 8;
        float w1c[2 * LAG];
        #pragma unroll
        for (int k = 0; k < 2 * LAG; ++k) w1c[k] = w_msg1[k * HID + col];
        const float bm = b_msg1[col];
        float vacc[3];
        #pragma unroll
        for (int tt = 0; tt < 3; ++tt) {
            float va = 0.f;
            #pragma unroll
            for (int l = 0; l < LAG; ++l) va = fmaf(feats[n][tt + l], w1c[LAG + l], va);
            vacc[tt] = va;
        }
        #pragma unroll
        for (int tt = 0; tt < 3; ++tt) {
            #pragma unroll
            for (int e8 = 0; e8 < 16; ++e8) {
                const int ei = dup * 16 + e8;
                f16 val = (f16)0.f;
                if (ei < EPN) {
                    const int j = ei + (ei >= n);
                    float ua = bm;
                    #pragma unroll
                    for (int l = 0; l < LAG; ++l) ua = fmaf(feats[j][tt + l], w1c[l], ua);
                    val = (f16)fmaxf(ua + vacc[tt], 0.f);
                }
                a_lds[tt * 32 + ei][col] = val;
            }
        }
    }

    // ---- B prefetch (frag-order: chunk = col/16 = w*2+nt) ----
    const f16* bbase = w2frag + (lane << 3);
    f16x8 b0[2], b1[2], b2[2];
    #pragma unroll
    for (int nt = 0; nt < 2; ++nt) {
        b0[nt] = *(const f16x8*)(bbase + (((w * 2 + nt) * 8 + 0) << 9));
        b1[nt] = *(const f16x8*)(bbase + (((w * 2 + nt) * 8 + 1) << 9));
    }
    floatx4 acc[6][2];
    #pragma unroll
    for (int mt = 0; mt < 6; ++mt)
        #pragma unroll
        for (int nt = 0; nt < 2; ++nt)
            acc[mt][nt] = (floatx4){0.f, 0.f, 0.f, 0.f};

    __syncthreads();   // A staged

    #pragma unroll
    for (int kc = 0; kc < 8; ++kc) {
        if (kc < 6) {
            #pragma unroll
            for (int nt = 0; nt < 2; ++nt)
                b2[nt] = *(const f16x8*)(bbase + (((w * 2 + nt) * 8 + kc + 2) << 9));
        }
        f16x8 af[6];
        #pragma unroll
        for (int mt = 0; mt < 6; ++mt)
            af[mt] = *(const f16x8*)&a_lds[mt * 16 + m15][kc * KC + q * 8];
        #pragma unroll
        for (int nt = 0; nt < 2; ++nt)
            #pragma unroll
            for (int mt = 0; mt < 6; ++mt)
                acc[mt][nt] = __builtin_amdgcn_mfma_f32_16x16x32_f16(af[mt], b0[nt], acc[mt][nt], 0, 0, 0);
        #pragma unroll
        for (int nt = 0; nt < 2; ++nt) { b0[nt] = b1[nt]; b1[nt] = b2[nt]; }
    }

    // ---- epilogue: msg = relu(acc + b2) * edgeval ; sum edges -> agg[b,t,n,:] ----
    float b2v[2];
    #pragma unroll
    for (int nt = 0; nt < 2; ++nt) b2v[nt] = b_msg2[wbase + nt * 16 + m15];

    #pragma unroll
    for (int tt = 0; tt < 3; ++tt) {
        const int t = t0 + tt;
        #pragma unroll
        for (int nt = 0; nt < 2; ++nt) {
            float part = 0.f;
            #pragma unroll
            for (int ml = 0; ml < 2; ++ml) {
                const int mt = tt * 2 + ml;
                #pragma unroll
                for (int reg = 0; reg < 4; ++reg) {
                    const int ei = (ml * 16 + q * 4 + reg);    // C-layout row = q*4+reg
                    part += ev_lds[ei] * fmaxf(acc[mt][nt][reg] + b2v[nt], 0.f);
                }
            }
            part += __shfl_xor(part, 16, 64);
            part += __shfl_xor(part, 32, 64);
            if (q == 0)
                agg[((((b * TM + t) * NA + n) << 8) + wbase + nt * 16 + m15)] = (f16)part;
        }
    }
}

// ---------------------------------------------------------------- K3: out MLP 288->256->256->1 (r7-proven)
__global__ __launch_bounds__(256) void k3_out(
    const f16* __restrict__ agg, const float* __restrict__ inputs,
    const f16* __restrict__ w1frag, const f16* __restrict__ w2ofrag,
    const float* __restrict__ b_out1, const float* __restrict__ b_out2,
    const float* __restrict__ w_out3, const float* __restrict__ b_out3,
    float* __restrict__ out)
{
    __shared__ f16 a1[16][288 + APAD];
    __shared__ float red[4][16];

    const int R0 = blockIdx.x * 16;
    const int tid = threadIdx.x;
    const int lane = tid & 63, w = tid >> 6;
    const int q = lane >> 4, m15 = lane & 15;
    const int wbase = w * 64;

    #pragma unroll
    for (int i = 0; i < 2; ++i) {
        const int task = i * 256 + tid;
        const int row = task >> 5, c = task & 31;
        const int R = R0 + row;
        f16x8 val;
        if (R < NROWS) {
            val = *(const f16x8*)&agg[(R << 8) + c * 8];
        } else {
            for (int x = 0; x < 8; ++x) val[x] = (f16)0.f;
        }
        *(f16x8*)&a1[row][c * 8] = val;
    }
    if (tid < 16) {
        const int R = R0 + tid;
        if (R < NROWS) {
            const int b = R / (TM * NA), rem = R % (TM * NA);
            const int t = rem / NA, n = rem % NA;
            const float* ip = inputs + (b * NA + n) * TT + t;
            #pragma unroll
            for (int l = 0; l < LAG; ++l) a1[tid][256 + l] = (f16)ip[l];
            #pragma unroll
            for (int k = 261; k < 288; ++k) a1[tid][k] = (f16)0.f;
        } else {
            for (int k = 256; k < 288; ++k) a1[tid][k] = (f16)0.f;
        }
    }

    floatx4 acc[4];
    #pragma unroll
    for (int nt = 0; nt < 4; ++nt) acc[nt] = (floatx4){0.f, 0.f, 0.f, 0.f};

    const f16* b1base = w1frag + (lane << 3);
    f16x8 bcur[4], bnxt[4];
    #pragma unroll
    for (int nt = 0; nt < 4; ++nt)
        bcur[nt] = *(const f16x8*)(b1base + (((w * 4 + nt) * 9 + 0) << 9));

    __syncthreads();

    #pragma unroll
    for (int kc = 0; kc < 9; ++kc) {
        if (kc < 8) {
            #pragma unroll
            for (int nt = 0; nt < 4; ++nt)
                bnxt[nt] = *(const f16x8*)(b1base + (((w * 4 + nt) * 9 + kc + 1) << 9));
        }
        const f16x8 af = *(const f16x8*)&a1[m15][kc * KC + q * 8];
        #pragma unroll
        for (int nt = 0; nt < 4; ++nt)
            acc[nt] = __builtin_amdgcn_mfma_f32_16x16x32_f16(af, bcur[nt], acc[nt], 0, 0, 0);
        #pragma unroll
        for (int nt = 0; nt < 4; ++nt) bcur[nt] = bnxt[nt];
    }
    __syncthreads();

    {
        float b1v[4];
        #pragma unroll
        for (int nt = 0; nt < 4; ++nt) b1v[nt] = b_out1[wbase + nt * 16 + m15];
        #pragma unroll
        for (int nt = 0; nt < 4; ++nt)
            #pragma unroll
            for (int reg = 0; reg < 4; ++reg)
                a1[q * 4 + reg][wbase + nt * 16 + m15] =
                    (f16)fmaxf(acc[nt][reg] + b1v[nt], 0.f);
    }
    #pragma unroll
    for (int nt = 0; nt < 4; ++nt) acc[nt] = (floatx4){0.f, 0.f, 0.f, 0.f};

    const f16* b2base = w2ofrag + (lane << 3);
    #pragma unroll
    for (int nt = 0; nt < 4; ++nt)
        bcur[nt] = *(const f16x8*)(b2base + (((w * 4 + nt) * 8 + 0) << 9));

    __syncthreads();

    #pragma unroll
    for (int kc = 0; kc < 8; ++kc) {
        if (kc < 7) {
            #pragma unroll
            for (int nt = 0; nt < 4; ++nt)
                bnxt[nt] = *(const f16x8*)(b2base + (((w * 4 + nt) * 8 + kc + 1) << 9));
        }
        const f16x8 af = *(const f16x8*)&a1[m15][kc * KC + q * 8];
        #pragma unroll
        for (int nt = 0; nt < 4; ++nt)
            acc[nt] = __builtin_amdgcn_mfma_f32_16x16x32_f16(af, bcur[nt], acc[nt], 0, 0, 0);
        #pragma unroll
        for (int nt = 0; nt < 4; ++nt) bcur[nt] = bnxt[nt];
    }

    {
        float b2v[4], w3v[4];
        #pragma unroll
        for (int nt = 0; nt < 4; ++nt) {
            const int col = wbase + nt * 16 + m15;
            b2v[nt] = b_out2[col];
            w3v[nt] = w_out3[col];
        }
        #pragma unroll
        for (int reg = 0; reg < 4; ++reg) {
            float p = 0.f;
            #pragma unroll
            for (int nt = 0; nt < 4; ++nt)
                p += fmaxf(acc[nt][reg] + b2v[nt], 0.f) * w3v[nt];
            p += __shfl_xor(p, 1, 64);
            p += __shfl_xor(p, 2, 64);
            p += __shfl_xor(p, 4, 64);
            p += __shfl_xor(p, 8, 64);
            if (m15 == 0) red[w][q * 4 + reg] = p;
        }
    }
    __syncthreads();
    if (tid < 16) {
        const int R = R0 + tid;
        if (R < NROWS) {
            const float val = red[0][tid] + red[1][tid] + red[2][tid] + red[3][tid] + b_out3[0];
            const int b = R / (TM * NA), rem = R % (TM * NA);
            const int t = rem / NA, n = rem % NA;
            out[(b * NA + n) * TM + t] = val;
        }
    }
}

// ----------------------------------------------------------------
extern "C" void kernel_launch(void* const* d_in, const int* in_sizes, int n_in,
                              void* d_out, int out_size, void* d_ws, size_t ws_size,
                              hipStream_t stream) {
    const float* inputs  = (const float*)d_in[0];
    const float* mu      = (const float*)d_in[1];
    const float* logvar  = (const float*)d_in[2];
    const float* eps     = (const float*)d_in[3];
    const float* w_msg1  = (const float*)d_in[6];
    const float* b_msg1  = (const float*)d_in[7];
    const float* w_msg2  = (const float*)d_in[8];
    const float* b_msg2  = (const float*)d_in[9];
    const float* w_out1  = (const float*)d_in[10];
    const float* b_out1  = (const float*)d_in[11];
    const float* w_out2  = (const float*)d_in[12];
    const float* b_out2  = (const float*)d_in[13];
    const float* w_out3  = (const float*)d_in[14];
    const float* b_out3  = (const float*)d_in[15];
    float* out = (float*)d_out;

    // workspace (f16): aggw (6 MB) + frag-order W2, Wout1, Wout2 (~0.54 MB)
    f16* aggw    = (f16*)d_ws;
    f16* w2frag  = aggw    + NROWS * HID;
    f16* w1frag  = w2frag  + W2F_ELEMS;
    f16* w2ofrag = w1frag  + W1F_ELEMS;

    hipLaunchKernelGGL(k1_frag, dim3(100), dim3(256), 0, stream,
                       w_msg2, w_out1, w_out2, w2frag, w1frag, w2ofrag);
    hipLaunchKernelGGL(k2_msg, dim3(NB * NA * TB3), dim3(512), 0, stream,
                       inputs, w_msg1, b_msg1, w2frag, mu, logvar, eps, b_msg2, aggw);
    hipLaunchKernelGGL(k3_out, dim3((NROWS + 15) / 16), dim3(256), 0, stream,
                       aggw, inputs, w1frag, w2ofrag, b_out1, b_out2, w_out3, b_out3, out);
}